// Round 1
// baseline (683.409 us; speedup 1.0000x reference)
//
#include <hip/hip_runtime.h>

#define BB 512
#define SS 512
#define LL 128

// ---------------- label score: ls[b] = point_score + trans_score ----------------
__global__ void __launch_bounds__(256) crf_label_score_kernel(
    const float* __restrict__ input, const int* __restrict__ label,
    const int* __restrict__ length, const float* __restrict__ trans,
    float* __restrict__ ls)
{
    const int b = blockIdx.x;
    const int tid = threadIdx.x;
    int len = length[b];
    len = len < 1 ? 1 : (len > SS ? SS : len);

    float acc = 0.f;
    for (int t = tid; t < len; t += 256) {
        const int lab = label[b * SS + t];
        acc += input[((size_t)b * SS + t) * LL + lab];
        if (t + 1 < len) {
            const int lab2 = label[b * SS + t + 1];
            acc += trans[lab * LL + lab2];
        }
    }
    // block-sum reduce (4 waves)
    #pragma unroll
    for (int off = 32; off > 0; off >>= 1) acc += __shfl_xor(acc, off, 64);
    __shared__ float wpart[4];
    if ((tid & 63) == 0) wpart[tid >> 6] = acc;
    __syncthreads();
    if (tid == 0) ls[b] = wpart[0] + wpart[1] + wpart[2] + wpart[3];
}

// ---------------- forward algorithm: out[b] = logZ - ls[b] ----------------
// one block (128 threads) per batch; thread j owns state j.
// alpha_new[j] = M + log( sum_i exp(alpha_i - M) * expT[i][j] ) + x[t][j]
__global__ void __launch_bounds__(128) crf_forward_kernel(
    const float* __restrict__ input, const int* __restrict__ length,
    const float* __restrict__ trans, const float* __restrict__ ls,
    float* __restrict__ out)
{
    const int b = blockIdx.x;
    const int j = threadIdx.x;   // 0..127
    int len = length[b];
    len = len < 1 ? 1 : (len > SS ? SS : len);

    __shared__ float e_lds[LL];
    __shared__ float wred[2];
    __shared__ float wsum[2];

    // thread j holds column j of exp(trans): expT[i][j], i = 0..127
    float tcol[LL];
    #pragma unroll
    for (int i = 0; i < LL; ++i)
        tcol[i] = __expf(trans[i * LL + j]);   // coalesced per i

    const float* __restrict__ xb = input + (size_t)b * SS * LL;
    float alpha = xb[j];   // t = 0

    for (int t = 1; t < len; ++t) {
        const float xt = xb[t * LL + j];   // prefetch; independent of recursion

        // global max of alpha over the block
        float m = alpha;
        #pragma unroll
        for (int off = 32; off > 0; off >>= 1) m = fmaxf(m, __shfl_xor(m, off, 64));
        if ((j & 63) == 0) wred[j >> 6] = m;
        __syncthreads();
        const float M = fmaxf(wred[0], wred[1]);

        e_lds[j] = __expf(alpha - M);
        __syncthreads();

        // matvec: sum_i e[i] * tcol[i]; LDS float4 reads are same-address -> broadcast
        float acc0 = 0.f, acc1 = 0.f, acc2 = 0.f, acc3 = 0.f;
        const float4* __restrict__ e4 = reinterpret_cast<const float4*>(e_lds);
        #pragma unroll
        for (int i = 0; i < LL / 4; ++i) {
            const float4 ev = e4[i];
            acc0 = fmaf(ev.x, tcol[4 * i + 0], acc0);
            acc1 = fmaf(ev.y, tcol[4 * i + 1], acc1);
            acc2 = fmaf(ev.z, tcol[4 * i + 2], acc2);
            acc3 = fmaf(ev.w, tcol[4 * i + 3], acc3);
        }
        alpha = M + __logf((acc0 + acc1) + (acc2 + acc3)) + xt;
    }

    // final logsumexp over the 128 states
    float m = alpha;
    #pragma unroll
    for (int off = 32; off > 0; off >>= 1) m = fmaxf(m, __shfl_xor(m, off, 64));
    if ((j & 63) == 0) wred[j >> 6] = m;
    __syncthreads();
    const float M = fmaxf(wred[0], wred[1]);

    float ex = __expf(alpha - M);
    #pragma unroll
    for (int off = 32; off > 0; off >>= 1) ex += __shfl_xor(ex, off, 64);
    if ((j & 63) == 0) wsum[j >> 6] = ex;
    __syncthreads();

    if (j == 0) out[b] = M + __logf(wsum[0] + wsum[1]) - ls[b];
}

extern "C" void kernel_launch(void* const* d_in, const int* in_sizes, int n_in,
                              void* d_out, int out_size, void* d_ws, size_t ws_size,
                              hipStream_t stream) {
    const float* input  = (const float*)d_in[0];   // (B,S,L) f32
    const int*   label  = (const int*)d_in[1];     // (B,S) i32
    const int*   length = (const int*)d_in[2];     // (B,) i32
    const float* trans  = (const float*)d_in[3];   // (L,L) f32
    float* out = (float*)d_out;                    // (B,1) f32
    float* ls  = (float*)d_ws;                     // B floats scratch

    crf_label_score_kernel<<<BB, 256, 0, stream>>>(input, label, length, trans, ls);
    crf_forward_kernel<<<BB, 128, 0, stream>>>(input, length, trans, ls, out);
}

// Round 2
// 561.333 us; speedup vs baseline: 1.2175x; 1.2175x over previous
//
#include <hip/hip_runtime.h>

#define BB 512
#define SS 512
#define LL 128

// ---------------- label score: ls[b] = point_score + trans_score ----------------
__global__ void __launch_bounds__(256) crf_label_score_kernel(
    const float* __restrict__ input, const int* __restrict__ label,
    const int* __restrict__ length, const float* __restrict__ trans,
    float* __restrict__ ls)
{
    const int b = blockIdx.x;
    const int tid = threadIdx.x;
    int len = length[b];
    len = len < 1 ? 1 : (len > SS ? SS : len);

    float acc = 0.f;
    for (int t = tid; t < len; t += 256) {
        const int lab = label[b * SS + t];
        acc += input[((size_t)b * SS + t) * LL + lab];
        if (t + 1 < len) {
            const int lab2 = label[b * SS + t + 1];
            acc += trans[lab * LL + lab2];
        }
    }
    #pragma unroll
    for (int off = 32; off > 0; off >>= 1) acc += __shfl_xor(acc, off, 64);
    __shared__ float wpart[4];
    if ((tid & 63) == 0) wpart[tid >> 6] = acc;
    __syncthreads();
    if (tid == 0) ls[b] = wpart[0] + wpart[1] + wpart[2] + wpart[3];
}

// ---------------- forward algorithm: out[b] = logZ - ls[b] ----------------
// 256 threads/block, one block per batch. thread = (state j = tid>>1, half h = tid&1).
// Each thread owns 64 expT registers: tcol[k] = exp(trans[h*64+k][j]).
// alpha_new[j] = M + log( sum_i exp(alpha_i - M) * expT[i][j] ) + x[t][j]
// M is the ONE-STEP-STALE max (lse is exactly M-invariant; only fp-range matters,
// drift per step <= ~12 so exp args stay well inside f32 range).
__global__ void __launch_bounds__(256) crf_forward_kernel(
    const float* __restrict__ input, const int* __restrict__ length,
    const float* __restrict__ trans, const float* __restrict__ ls,
    float* __restrict__ out)
{
    const int b    = blockIdx.x;
    const int tid  = threadIdx.x;   // 0..255
    const int j    = tid >> 1;      // state 0..127
    const int h    = tid & 1;       // i-range half
    const int w    = tid >> 6;      // wave 0..3
    const int lane = tid & 63;

    int len = length[b];
    len = len < 1 ? 1 : (len > SS ? SS : len);

    __shared__ float e_lds[2][LL];
    __shared__ float wmax[2][4];
    __shared__ float wpre[4];
    __shared__ float wfin[8];

    // 64 registers of exp(trans): rows h*64 .. h*64+63, column j
    float tcol[64];
    #pragma unroll
    for (int k = 0; k < 64; ++k)
        tcol[k] = __expf(trans[(h * 64 + k) * LL + j]);

    const float* __restrict__ xb = input + (size_t)b * SS * LL;
    float alpha = xb[j];   // t = 0 (both lanes of the pair hold the same alpha[j])

    // exact max of alpha0 -> M_cur
    {
        float m = alpha;
        #pragma unroll
        for (int off = 2; off <= 32; off <<= 1) m = fmaxf(m, __shfl_xor(m, off, 64));
        if (lane == 0) wpre[w] = m;
    }
    __syncthreads();
    float M_cur = fmaxf(fmaxf(wpre[0], wpre[1]), fmaxf(wpre[2], wpre[3]));

    // depth-3 x prefetch ring
    float x_a = (1 < len) ? xb[1 * LL + j] : 0.f;
    float x_b = (2 < len) ? xb[2 * LL + j] : 0.f;
    float x_c = (3 < len) ? xb[3 * LL + j] : 0.f;

    for (int t = 1; t < len; ++t) {
        const int buf = t & 1;
        const float xt = x_a;
        x_a = x_b; x_b = x_c;
        const int tf = t + 3;
        x_c = (tf < len) ? xb[tf * LL + j] : 0.f;   // uniform branch per block

        // e from (possibly stale) M_cur; alpha_new uses the SAME M_cur -> exact
        const float e = __expf(alpha - M_cur);
        if (h == 0) e_lds[buf][j] = e;

        // wave-partial max of alpha_{t-1} (next step's M), off the critical path
        float mm = alpha;
        #pragma unroll
        for (int off = 2; off <= 32; off <<= 1) mm = fmaxf(mm, __shfl_xor(mm, off, 64));
        if (lane == 0) wmax[buf][w] = mm;

        __syncthreads();

        // matvec over this thread's 64 i's; float4 LDS reads are 2-address
        // broadcast per wave (2-way, free)
        float acc0 = 0.f, acc1 = 0.f, acc2 = 0.f, acc3 = 0.f;
        const float4* __restrict__ e4 =
            reinterpret_cast<const float4*>(&e_lds[buf][h * 64]);
        #pragma unroll
        for (int k = 0; k < 16; ++k) {
            const float4 ev = e4[k];
            acc0 = fmaf(ev.x, tcol[4 * k + 0], acc0);
            acc1 = fmaf(ev.y, tcol[4 * k + 1], acc1);
            acc2 = fmaf(ev.z, tcol[4 * k + 2], acc2);
            acc3 = fmaf(ev.w, tcol[4 * k + 3], acc3);
        }
        float s = (acc0 + acc1) + (acc2 + acc3);
        s += __shfl_xor(s, 1, 64);               // combine the pair halves

        alpha = M_cur + __logf(s) + xt;

        // adopt max(alpha_{t-1}) as next step's M (stale by exactly 1)
        M_cur = fmaxf(fmaxf(wmax[buf][0], wmax[buf][1]),
                      fmaxf(wmax[buf][2], wmax[buf][3]));
    }

    // final logsumexp over the 128 states (each state duplicated on a lane pair)
    {
        float mf = alpha;
        #pragma unroll
        for (int off = 2; off <= 32; off <<= 1) mf = fmaxf(mf, __shfl_xor(mf, off, 64));
        if (lane == 0) wfin[w] = mf;
    }
    __syncthreads();
    const float M = fmaxf(fmaxf(wfin[0], wfin[1]), fmaxf(wfin[2], wfin[3]));

    float ex = (h == 0) ? __expf(alpha - M) : 0.f;  // count each state once
    #pragma unroll
    for (int off = 1; off <= 32; off <<= 1) ex += __shfl_xor(ex, off, 64);
    if (lane == 0) wfin[4 + w] = ex;
    __syncthreads();

    if (tid == 0)
        out[b] = M + __logf(wfin[4] + wfin[5] + wfin[6] + wfin[7]) - ls[b];
}

extern "C" void kernel_launch(void* const* d_in, const int* in_sizes, int n_in,
                              void* d_out, int out_size, void* d_ws, size_t ws_size,
                              hipStream_t stream) {
    const float* input  = (const float*)d_in[0];   // (B,S,L) f32
    const int*   label  = (const int*)d_in[1];     // (B,S) i32
    const int*   length = (const int*)d_in[2];     // (B,) i32
    const float* trans  = (const float*)d_in[3];   // (L,L) f32
    float* out = (float*)d_out;                    // (B,1) f32
    float* ls  = (float*)d_ws;                     // B floats scratch

    crf_label_score_kernel<<<BB, 256, 0, stream>>>(input, label, length, trans, ls);
    crf_forward_kernel<<<BB, 256, 0, stream>>>(input, length, trans, ls, out);
}

// Round 5
// 560.075 us; speedup vs baseline: 1.2202x; 1.0022x over previous
//
#include <hip/hip_runtime.h>

#define BB 512
#define SS 512
#define LL 128

// Fused CRF loss: label score (prologue) + forward algorithm, one block per batch.
// 256 threads: thread = (state j = tid>>1, half h = tid&1). Each thread keeps 64
// exp(trans) values in REGISTERS (launch_bounds(256,2) -> VGPR cap 256, 2 blocks/CU).
// alpha_new[j] = M + log( sum_i exp(alpha_i - M) * expT[i][j] ) + x[t][j]
// M is one-step-stale max (lse is exactly shift-invariant; only fp-range matters).
__global__ void __launch_bounds__(256, 2) crf_fused_kernel(
    const float* __restrict__ input, const int* __restrict__ label,
    const int* __restrict__ length, const float* __restrict__ trans,
    float* __restrict__ out)
{
    const int b    = blockIdx.x;
    const int tid  = threadIdx.x;   // 0..255
    const int j    = tid >> 1;      // state 0..127
    const int h    = tid & 1;       // i-range half
    const int w    = tid >> 6;      // wave 0..3
    const int lane = tid & 63;

    int len = length[b];
    len = len < 1 ? 1 : (len > SS ? SS : len);

    __shared__ float e_lds[2][LL];
    __shared__ float wmax[2][4];
    __shared__ float wpre[4];
    __shared__ float wfin[8];
    __shared__ float lspart[4];

    const float* __restrict__ xb = input + (size_t)b * SS * LL;

    // ---------- fused label score: point + transition ----------
    float lsacc = 0.f;
    for (int t = tid; t < len; t += 256) {          // <= 2 iterations
        const int lab = label[b * SS + t];
        lsacc += xb[(size_t)t * LL + lab];
        if (t + 1 < len)
            lsacc += trans[lab * LL + label[b * SS + t + 1]];
    }
    #pragma unroll
    for (int off = 32; off > 0; off >>= 1) lsacc += __shfl_xor(lsacc, off, 64);
    if (lane == 0) lspart[w] = lsacc;

    // ---------- transition column in registers ----------
    // thread holds expT rows h*64 .. h*64+63, column j
    float tcol[64];
    #pragma unroll
    for (int k = 0; k < 64; ++k)
        tcol[k] = __expf(trans[(h * 64 + k) * LL + j]);

    float alpha = xb[j];   // t = 0 (pair-duplicated)

    // exact max of alpha0 -> M_cur
    {
        float m = alpha;
        #pragma unroll
        for (int off = 2; off <= 32; off <<= 1) m = fmaxf(m, __shfl_xor(m, off, 64));
        if (lane == 0) wpre[w] = m;
    }
    __syncthreads();
    float M_cur = fmaxf(fmaxf(wpre[0], wpre[1]), fmaxf(wpre[2], wpre[3]));

    // depth-3 x prefetch ring
    float x_a = (1 < len) ? xb[1 * LL + j] : 0.f;
    float x_b = (2 < len) ? xb[2 * LL + j] : 0.f;
    float x_c = (3 < len) ? xb[3 * LL + j] : 0.f;

    for (int t = 1; t < len; ++t) {
        const int buf = t & 1;
        const float xt = x_a;
        x_a = x_b; x_b = x_c;
        const int tf = t + 3;
        x_c = (tf < len) ? xb[(size_t)tf * LL + j] : 0.f;   // uniform per block

        const float e = __expf(alpha - M_cur);
        if (h == 0) e_lds[buf][j] = e;

        // next step's (stale) max, off the critical path
        float mm = alpha;
        #pragma unroll
        for (int off = 2; off <= 32; off <<= 1) mm = fmaxf(mm, __shfl_xor(mm, off, 64));
        if (lane == 0) wmax[buf][w] = mm;

        __syncthreads();

        // matvec over this thread's 64 i's (LDS float4 reads: 2-address broadcast)
        float acc0 = 0.f, acc1 = 0.f, acc2 = 0.f, acc3 = 0.f;
        const float4* __restrict__ e4 =
            reinterpret_cast<const float4*>(&e_lds[buf][h * 64]);
        #pragma unroll
        for (int k = 0; k < 16; ++k) {
            const float4 ev = e4[k];
            acc0 = fmaf(ev.x, tcol[4 * k + 0], acc0);
            acc1 = fmaf(ev.y, tcol[4 * k + 1], acc1);
            acc2 = fmaf(ev.z, tcol[4 * k + 2], acc2);
            acc3 = fmaf(ev.w, tcol[4 * k + 3], acc3);
        }
        float s = (acc0 + acc1) + (acc2 + acc3);
        s += __shfl_xor(s, 1, 64);               // combine pair halves

        alpha = M_cur + __logf(s) + xt;

        M_cur = fmaxf(fmaxf(wmax[buf][0], wmax[buf][1]),
                      fmaxf(wmax[buf][2], wmax[buf][3]));
    }

    // ---------- final logsumexp ----------
    {
        float mf = alpha;
        #pragma unroll
        for (int off = 2; off <= 32; off <<= 1) mf = fmaxf(mf, __shfl_xor(mf, off, 64));
        if (lane == 0) wfin[w] = mf;
    }
    __syncthreads();
    const float M = fmaxf(fmaxf(wfin[0], wfin[1]), fmaxf(wfin[2], wfin[3]));

    float ex = (h == 0) ? __expf(alpha - M) : 0.f;  // count each state once
    #pragma unroll
    for (int off = 1; off <= 32; off <<= 1) ex += __shfl_xor(ex, off, 64);
    if (lane == 0) wfin[4 + w] = ex;
    __syncthreads();

    if (tid == 0)
        out[b] = M + __logf(wfin[4] + wfin[5] + wfin[6] + wfin[7])
               - (lspart[0] + lspart[1] + lspart[2] + lspart[3]);
}

extern "C" void kernel_launch(void* const* d_in, const int* in_sizes, int n_in,
                              void* d_out, int out_size, void* d_ws, size_t ws_size,
                              hipStream_t stream) {
    const float* input  = (const float*)d_in[0];   // (B,S,L) f32
    const int*   label  = (const int*)d_in[1];     // (B,S) i32
    const int*   length = (const int*)d_in[2];     // (B,) i32
    const float* trans  = (const float*)d_in[3];   // (L,L) f32
    float* out = (float*)d_out;                    // (B,1) f32

    crf_fused_kernel<<<BB, 256, 0, stream>>>(input, label, length, trans, out);
}